// Round 5
// baseline (371.323 us; speedup 1.0000x reference)
//
#include <hip/hip_runtime.h>
#include <float.h>

// Tropical (max-plus) linear: y[b,o] = max_i (x[b,i] + W[o,i])
// B=512, I=1024, O=1024, fp32. No MFMA (max-plus semiring) -> fp32 VALU.
//
// Round-5 design:
//  * Pre-transpose x->xT[I][B], W->wT[I][O] (once, ~2.5 us; r2-verified kernel).
//  * Main: 128x128 tile, 8x8/thread, k-major LDS [k][row] (r2's compute layout,
//    measured 0 bank conflicts). ALL inner-loop ds_read_b128 use STATIC
//    immediate offsets from one per-thread base -> zero per-read address VALU,
//    clean compiler pipelining (r3/r4's runtime-swizzled offsets kept the
//    kernel at ~4x the LDS floor).
//  * Staging: global_load_lds width 16 from xT/wT rows (no swizzle, no
//    ds_write), double-buffered, KT=32.
//  * acc as f32x4 over o; splat-x + v_pk_add_f32 + v_max3_f32 = 1 VALU/out/k.
//    Live set ~130 VGPR (acc 64 + frags 32) -> fits 256 cap at 2 blocks/CU.
//  * KSPLIT=16 -> 512 blocks = 2/CU; partial slabs in d_ws, float4 reduce.

#define B_DIM 512
#define I_DIM 1024
#define O_DIM 1024
#define BT 128
#define OT 128
#define KT 32

typedef float f32x4 __attribute__((ext_vector_type(4)));

__device__ __forceinline__ void g2lds16(const float* g, float* l) {
    __builtin_amdgcn_global_load_lds(
        (const __attribute__((address_space(1))) void*)g,
        (__attribute__((address_space(3))) void*)l, 16, 0, 0);
}

template <int KB>   // k handled per block
__global__ __launch_bounds__(256, 2) void trop_main(
    const float* __restrict__ xT,   // [I_DIM][B_DIM]
    const float* __restrict__ wT,   // [I_DIM][O_DIM]
    float* __restrict__ part)       // [KSPLIT][B_DIM][O_DIM]  (or y if z==1)
{
    constexpr int NCH = KB / KT;
    static_assert(KB % KT == 0, "");
    __shared__ __align__(16) float xs[2][KT * BT];   // [k][b], 16 KB/buf
    __shared__ __align__(16) float ws[2][KT * OT];   // [k][o], 16 KB/buf

    const int tid  = threadIdx.x;
    const int to   = tid & 15;      // o-quad selector
    const int tb   = tid >> 4;      // b-quad selector
    const int wave = tid >> 6;
    const int lane = tid & 63;
    const int o0 = blockIdx.x * OT;
    const int b0 = blockIdx.y * BT;
    const int kz = blockIdx.z;
    const int kbase = kz * KB;

    const int rk = lane >> 5;           // k-subrow within one 1KB DMA (2 k-rows)
    const int cb = (lane & 31) * 4;     // col offset in floats (lane*16B)

    f32x4 acc[8][2];   // [ii = g*4+u over b][h] , each f32x4 over o-quad v
    #pragma unroll
    for (int i = 0; i < 8; ++i) {
        acc[i][0] = (f32x4)(-FLT_MAX);
        acc[i][1] = (f32x4)(-FLT_MAX);
    }

    auto stage = [&](int c, int buf) {
        const int k0 = kbase + c * KT;
        #pragma unroll
        for (int i = 0; i < 4; ++i) {
            const int t = wave * 4 + i;                 // 0..15 -> k-pair
            g2lds16(&xT[(size_t)(k0 + 2 * t + rk) * B_DIM + b0 + cb],
                    &xs[buf][t * 256]);
        }
        #pragma unroll
        for (int i = 0; i < 4; ++i) {
            const int t = wave * 4 + i;
            g2lds16(&wT[(size_t)(k0 + 2 * t + rk) * O_DIM + o0 + cb],
                    &ws[buf][t * 256]);
        }
    };

    auto compute = [&](int buf) {
        const float* xB = &xs[buf][4 * tb];   // per-thread base; all reads static off
        const float* wB = &ws[buf][4 * to];
        #pragma unroll
        for (int k = 0; k < KT; k += 2) {
            const f32x4 xa[2] = { *(const f32x4*)&xB[k * BT],
                                  *(const f32x4*)&xB[k * BT + 64] };
            const f32x4 xb[2] = { *(const f32x4*)&xB[(k + 1) * BT],
                                  *(const f32x4*)&xB[(k + 1) * BT + 64] };
            const f32x4 wa[2] = { *(const f32x4*)&wB[k * OT],
                                  *(const f32x4*)&wB[k * OT + 64] };
            const f32x4 wb[2] = { *(const f32x4*)&wB[(k + 1) * OT],
                                  *(const f32x4*)&wB[(k + 1) * OT + 64] };
            #pragma unroll
            for (int g = 0; g < 2; ++g)
                #pragma unroll
                for (int u = 0; u < 4; ++u) {
                    const float x0 = xa[g][u];
                    const float x1 = xb[g][u];
                    #pragma unroll
                    for (int h = 0; h < 2; ++h) {
                        const f32x4 s0 = wa[h] + x0;   // splat + v_pk_add_f32
                        const f32x4 s1 = wb[h] + x1;
                        f32x4 a = acc[g * 4 + u][h];
                        a.x = fmaxf(a.x, fmaxf(s0.x, s1.x));   // v_max3_f32
                        a.y = fmaxf(a.y, fmaxf(s0.y, s1.y));
                        a.z = fmaxf(a.z, fmaxf(s0.z, s1.z));
                        a.w = fmaxf(a.w, fmaxf(s0.w, s1.w));
                        acc[g * 4 + u][h] = a;
                    }
                }
        }
    };

    stage(0, 0);
    #pragma unroll
    for (int c = 0; c < NCH; ++c) {
        __syncthreads();                               // chunk c staged; prev reads done
        if (c + 1 < NCH) stage(c + 1, (c + 1) & 1);    // DMA overlaps compute
        compute(c & 1);
    }

    // epilogue: coalesced float4 stores (quarter-wave = 256B contiguous)
    float* pout = part + (size_t)kz * (B_DIM * O_DIM);
    #pragma unroll
    for (int g = 0; g < 2; ++g)
        #pragma unroll
        for (int u = 0; u < 4; ++u) {
            const int b = b0 + 64 * g + 4 * tb + u;
            #pragma unroll
            for (int h = 0; h < 2; ++h)
                *(f32x4*)&pout[(size_t)b * O_DIM + o0 + 64 * h + 4 * to] =
                    acc[g * 4 + u][h];
        }
}

// ---- 32x32 LDS tile transpose: out[c][r] = in[r][c]  (r2-verified)
__global__ __launch_bounds__(256) void transpose_k(
    const float* __restrict__ in, float* __restrict__ out, int R, int C)
{
    __shared__ float tile[32][33];
    const int tx = threadIdx.x;   // 0..31
    const int ty = threadIdx.y;   // 0..7
    const int r0 = blockIdx.y * 32;
    const int c0 = blockIdx.x * 32;
    #pragma unroll
    for (int i = 0; i < 4; ++i)
        tile[ty + 8 * i][tx] = in[(size_t)(r0 + ty + 8 * i) * C + c0 + tx];
    __syncthreads();
    #pragma unroll
    for (int i = 0; i < 4; ++i)
        out[(size_t)(c0 + ty + 8 * i) * R + r0 + tx] = tile[tx][ty + 8 * i];
}

template <int KS>
__global__ __launch_bounds__(256) void trop_reduce(
    const float* __restrict__ part, float* __restrict__ y)
{
    constexpr int N4 = B_DIM * O_DIM / 4;
    const int idx = blockIdx.x * 256 + threadIdx.x;
    const float4* p = (const float4*)part;
    float4 m = p[idx];
    #pragma unroll
    for (int s = 1; s < KS; ++s) {
        const float4 v = p[(size_t)s * N4 + idx];
        m.x = fmaxf(m.x, v.x); m.y = fmaxf(m.y, v.y);
        m.z = fmaxf(m.z, v.z); m.w = fmaxf(m.w, v.w);
    }
    ((float4*)y)[idx] = m;
}

// correctness-net fallback if d_ws is tiny (no transpose/slab space)
__global__ __launch_bounds__(256) void trop_naive(
    const float* __restrict__ x, const float* __restrict__ W,
    float* __restrict__ y)
{
    const int idx = blockIdx.x * 256 + threadIdx.x;
    const int b = idx / O_DIM, o = idx % O_DIM;
    float m = -FLT_MAX;
    for (int i = 0; i < I_DIM; ++i)
        m = fmaxf(m, x[b * I_DIM + i] + W[o * I_DIM + i]);
    y[idx] = m;
}

extern "C" void kernel_launch(void* const* d_in, const int* in_sizes, int n_in,
                              void* d_out, int out_size, void* d_ws, size_t ws_size,
                              hipStream_t stream) {
    const float* x = (const float*)d_in[0];
    const float* W = (const float*)d_in[1];
    float* y = (float*)d_out;

    const size_t slab  = (size_t)B_DIM * O_DIM * sizeof(float);     // 2 MB
    const size_t xT_sz = (size_t)B_DIM * I_DIM * sizeof(float);     // 2 MB
    const size_t wT_sz = (size_t)O_DIM * I_DIM * sizeof(float);     // 4 MB
    const dim3 rgrid(B_DIM * O_DIM / 4 / 256);

    auto run = [&](auto kmain, int ksplit, float* part, float* xT, float* wT) {
        transpose_k<<<dim3(I_DIM / 32, B_DIM / 32), dim3(32, 8), 0, stream>>>(x, xT, B_DIM, I_DIM);
        transpose_k<<<dim3(I_DIM / 32, O_DIM / 32), dim3(32, 8), 0, stream>>>(W, wT, O_DIM, I_DIM);
        kmain(dim3(O_DIM / OT, B_DIM / BT, ksplit), xT, wT, part);
    };

    if (ws_size >= 16 * slab + xT_sz + wT_sz) {          // 38 MB
        float* part = (float*)d_ws;
        float* xT = part + 16 * (B_DIM * O_DIM);
        float* wT = xT + B_DIM * I_DIM;
        run([&](dim3 g, const float* a, const float* b, float* p) {
                trop_main<I_DIM / 16><<<g, 256, 0, stream>>>(a, b, p); },
            16, part, xT, wT);
        trop_reduce<16><<<rgrid, 256, 0, stream>>>(part, y);
    } else if (ws_size >= 8 * slab + xT_sz + wT_sz) {    // 22 MB
        float* part = (float*)d_ws;
        float* xT = part + 8 * (B_DIM * O_DIM);
        float* wT = xT + B_DIM * I_DIM;
        run([&](dim3 g, const float* a, const float* b, float* p) {
                trop_main<I_DIM / 8><<<g, 256, 0, stream>>>(a, b, p); },
            8, part, xT, wT);
        trop_reduce<8><<<rgrid, 256, 0, stream>>>(part, y);
    } else if (ws_size >= xT_sz + wT_sz) {               // 6 MB: no K-split
        float* xT = (float*)d_ws;
        float* wT = xT + B_DIM * I_DIM;
        run([&](dim3 g, const float* a, const float* b, float* p) {
                trop_main<I_DIM><<<g, 256, 0, stream>>>(a, b, p); },
            1, y, xT, wT);
    } else {
        trop_naive<<<dim3(B_DIM * O_DIM / 256), 256, 0, stream>>>(x, W, y);
    }
}

// Round 6
// 92.157 us; speedup vs baseline: 4.0293x; 4.0293x over previous
//
#include <hip/hip_runtime.h>
#include <float.h>

// Tropical (max-plus) linear: y[b,o] = max_i (x[b,i] + W[o,i])
// B=512, I=1024, O=1024, fp32. No MFMA (max-plus semiring) -> fp32 VALU.
//
// Round-6 = the two verified-good halves recombined:
//  * Compute: round-2's k-major LDS layout with STATIC-offset float4 reads and
//    SCALAR float acc[8][8] / frag arrays (r2 measured: VGPR=108, 0 bank
//    conflicts, FETCH 10 MB -> clean codegen, no scratch).
//    Round-5's f32x4 register arrays caused allocator demotion -> 930 MB of
//    scratch HBM traffic (FETCH 568/WRITE 340 MB, VALUBusy 6%). Never again:
//    vector types only for LDS *loads*, scalars for register state.
//  * Epilogue: private slabs + float4 reduce (round-2's atomics cost ~77 us).
//  * Staging: pre-transposed xT/wT + global_load_lds width 16, double-buffered.
//  * KSPLIT=16 -> 512 blocks = 2 blocks/CU (LDS 64 KB/blk) for ds_read-latency
//    overlap across waves.
// Floors: LDS pipe 10.2 us, VALU 10.2 us (1.5 instr/MAC via v_max3_f32).

#define B_DIM 512
#define I_DIM 1024
#define O_DIM 1024
#define BT 128
#define OT 128
#define KT 32

__device__ __forceinline__ void g2lds16(const float* g, float* l) {
    __builtin_amdgcn_global_load_lds(
        (const __attribute__((address_space(1))) void*)g,
        (__attribute__((address_space(3))) void*)l, 16, 0, 0);
}

template <int KB>   // k handled per block
__global__ __launch_bounds__(256, 2) void trop_main(
    const float* __restrict__ xT,   // [I_DIM][B_DIM]
    const float* __restrict__ wT,   // [I_DIM][O_DIM]
    float* __restrict__ part)       // [KSPLIT][B_DIM][O_DIM] (or y if z==1)
{
    constexpr int NCH = KB / KT;
    static_assert(KB % KT == 0, "");
    __shared__ __align__(16) float xs[2][KT * BT];   // [k][b], 16 KB/buf
    __shared__ __align__(16) float ws[2][KT * OT];   // [k][o], 16 KB/buf

    const int tid  = threadIdx.x;
    const int to   = tid & 15;      // o-quad selector
    const int tb   = tid >> 4;      // b-quad selector
    const int wave = tid >> 6;
    const int lane = tid & 63;
    const int o0 = blockIdx.x * OT;
    const int b0 = blockIdx.y * BT;
    const int kz = blockIdx.z;
    const int kbase = kz * KB;

    const int rk = lane >> 5;           // k-subrow within one 1KB DMA
    const int cb = (lane & 31) * 4;     // col offset (lane*16B)

    float acc[8][8];                    // SCALAR regs — r2-verified codegen
    #pragma unroll
    for (int i = 0; i < 8; ++i)
        #pragma unroll
        for (int j = 0; j < 8; ++j)
            acc[i][j] = -FLT_MAX;

    auto stage = [&](int c, int buf) {
        const int k0 = kbase + c * KT;
        #pragma unroll
        for (int i = 0; i < 4; ++i) {
            const int t = wave * 4 + i;                 // wave-uniform LDS base
            g2lds16(&xT[(size_t)(k0 + 2 * t + rk) * B_DIM + b0 + cb],
                    &xs[buf][t * 256]);
        }
        #pragma unroll
        for (int i = 0; i < 4; ++i) {
            const int t = wave * 4 + i;
            g2lds16(&wT[(size_t)(k0 + 2 * t + rk) * O_DIM + o0 + cb],
                    &ws[buf][t * 256]);
        }
    };

    auto compute = [&](int buf) {
        const float* xB = &xs[buf][4 * tb];   // all reads: static imm offsets
        const float* wB = &ws[buf][4 * to];
        #pragma unroll 4
        for (int k = 0; k < KT; k += 2) {
            const float4 xa0 = *(const float4*)&xB[k * BT];
            const float4 xa1 = *(const float4*)&xB[k * BT + 64];
            const float4 xb0 = *(const float4*)&xB[(k + 1) * BT];
            const float4 xb1 = *(const float4*)&xB[(k + 1) * BT + 64];
            const float4 wa0 = *(const float4*)&wB[k * OT];
            const float4 wa1 = *(const float4*)&wB[k * OT + 64];
            const float4 wb0 = *(const float4*)&wB[(k + 1) * OT];
            const float4 wb1 = *(const float4*)&wB[(k + 1) * OT + 64];

            const float xa[8] = {xa0.x, xa0.y, xa0.z, xa0.w, xa1.x, xa1.y, xa1.z, xa1.w};
            const float xb[8] = {xb0.x, xb0.y, xb0.z, xb0.w, xb1.x, xb1.y, xb1.z, xb1.w};
            const float wa[8] = {wa0.x, wa0.y, wa0.z, wa0.w, wa1.x, wa1.y, wa1.z, wa1.w};
            const float wb[8] = {wb0.x, wb0.y, wb0.z, wb0.w, wb1.x, wb1.y, wb1.z, wb1.w};

            #pragma unroll
            for (int i = 0; i < 8; ++i)
                #pragma unroll
                for (int j = 0; j < 8; ++j) {
                    const float s0 = xa[i] + wa[j];
                    const float s1 = xb[i] + wb[j];
                    acc[i][j] = fmaxf(acc[i][j], fmaxf(s0, s1));   // v_max3_f32
                }
        }
    };

    stage(0, 0);
    for (int c = 0; c < NCH; ++c) {
        __syncthreads();                              // chunk c staged; prev reads done
        if (c + 1 < NCH) stage(c + 1, (c + 1) & 1);   // DMA overlaps compute
        compute(c & 1);
    }

    // epilogue: coalesced float4 stores into private slab
    float* pout = part + (size_t)kz * (B_DIM * O_DIM);
    #pragma unroll
    for (int i = 0; i < 8; ++i) {
        const int b = b0 + (i >> 2) * 64 + 4 * tb + (i & 3);
        float4 v0 = make_float4(acc[i][0], acc[i][1], acc[i][2], acc[i][3]);
        float4 v1 = make_float4(acc[i][4], acc[i][5], acc[i][6], acc[i][7]);
        *(float4*)&pout[(size_t)b * O_DIM + o0 + 4 * to]      = v0;
        *(float4*)&pout[(size_t)b * O_DIM + o0 + 64 + 4 * to] = v1;
    }
}

// ---- 32x32 LDS tile transpose: out[c][r] = in[r][c]  (r2-verified)
__global__ __launch_bounds__(256) void transpose_k(
    const float* __restrict__ in, float* __restrict__ out, int R, int C)
{
    __shared__ float tile[32][33];
    const int tx = threadIdx.x;   // 0..31
    const int ty = threadIdx.y;   // 0..7
    const int r0 = blockIdx.y * 32;
    const int c0 = blockIdx.x * 32;
    #pragma unroll
    for (int i = 0; i < 4; ++i)
        tile[ty + 8 * i][tx] = in[(size_t)(r0 + ty + 8 * i) * C + c0 + tx];
    __syncthreads();
    #pragma unroll
    for (int i = 0; i < 4; ++i)
        out[(size_t)(c0 + ty + 8 * i) * R + r0 + tx] = tile[tx][ty + 8 * i];
}

template <int KS>
__global__ __launch_bounds__(256) void trop_reduce(
    const float* __restrict__ part, float* __restrict__ y)
{
    constexpr int N4 = B_DIM * O_DIM / 4;
    const int idx = blockIdx.x * 256 + threadIdx.x;
    const float4* p = (const float4*)part;
    float4 m = p[idx];
    #pragma unroll
    for (int s = 1; s < KS; ++s) {
        const float4 v = p[(size_t)s * N4 + idx];
        m.x = fmaxf(m.x, v.x); m.y = fmaxf(m.y, v.y);
        m.z = fmaxf(m.z, v.z); m.w = fmaxf(m.w, v.w);
    }
    ((float4*)y)[idx] = m;
}

// correctness-net fallback if d_ws is tiny
__global__ __launch_bounds__(256) void trop_naive(
    const float* __restrict__ x, const float* __restrict__ W,
    float* __restrict__ y)
{
    const int idx = blockIdx.x * 256 + threadIdx.x;
    const int b = idx / O_DIM, o = idx % O_DIM;
    float m = -FLT_MAX;
    for (int i = 0; i < I_DIM; ++i)
        m = fmaxf(m, x[b * I_DIM + i] + W[o * I_DIM + i]);
    y[idx] = m;
}

extern "C" void kernel_launch(void* const* d_in, const int* in_sizes, int n_in,
                              void* d_out, int out_size, void* d_ws, size_t ws_size,
                              hipStream_t stream) {
    const float* x = (const float*)d_in[0];
    const float* W = (const float*)d_in[1];
    float* y = (float*)d_out;

    const size_t slab  = (size_t)B_DIM * O_DIM * sizeof(float);   // 2 MB
    const size_t xT_sz = (size_t)B_DIM * I_DIM * sizeof(float);   // 2 MB
    const size_t wT_sz = (size_t)O_DIM * I_DIM * sizeof(float);   // 4 MB
    const dim3 rgrid(B_DIM * O_DIM / 4 / 256);

    auto transpose_both = [&](float* xT, float* wT) {
        transpose_k<<<dim3(I_DIM / 32, B_DIM / 32), dim3(32, 8), 0, stream>>>(x, xT, B_DIM, I_DIM);
        transpose_k<<<dim3(I_DIM / 32, O_DIM / 32), dim3(32, 8), 0, stream>>>(W, wT, O_DIM, I_DIM);
    };

    if (ws_size >= 16 * slab + xT_sz + wT_sz) {          // 38 MB
        float* part = (float*)d_ws;
        float* xT = part + 16 * (B_DIM * O_DIM);
        float* wT = xT + B_DIM * I_DIM;
        transpose_both(xT, wT);
        trop_main<I_DIM / 16><<<dim3(O_DIM / OT, B_DIM / BT, 16), 256, 0, stream>>>(xT, wT, part);
        trop_reduce<16><<<rgrid, 256, 0, stream>>>(part, y);
    } else if (ws_size >= 8 * slab + xT_sz + wT_sz) {    // 22 MB
        float* part = (float*)d_ws;
        float* xT = part + 8 * (B_DIM * O_DIM);
        float* wT = xT + B_DIM * I_DIM;
        transpose_both(xT, wT);
        trop_main<I_DIM / 8><<<dim3(O_DIM / OT, B_DIM / BT, 8), 256, 0, stream>>>(xT, wT, part);
        trop_reduce<8><<<rgrid, 256, 0, stream>>>(part, y);
    } else if (ws_size >= xT_sz + wT_sz) {               // 6 MB: no K-split
        float* xT = (float*)d_ws;
        float* wT = xT + B_DIM * I_DIM;
        transpose_both(xT, wT);
        trop_main<I_DIM><<<dim3(O_DIM / OT, B_DIM / BT, 1), 256, 0, stream>>>(xT, wT, y);
    } else {
        trop_naive<<<dim3(B_DIM * O_DIM / 256), 256, 0, stream>>>(x, W, y);
    }
}